// Round 11
// baseline (2156.340 us; speedup 1.0000x reference)
//
#include <hip/hip_runtime.h>
#include <hip/hip_bf16.h>
#include <stdint.h>

namespace {

constexpr int MTOT = 8192;   // 4 * 2048 rows of x
constexpr int NTOT = 4096;   // OUT_DIM
constexpr int KTOT = 4096;   // IN_DIM

constexpr int BM = 256, BN = 256, BK = 32;
constexpr int NT = KTOT / BK;     // 128 K-tiles

typedef __attribute__((ext_vector_type(8))) short bf16x8;
typedef __attribute__((ext_vector_type(4))) float f32x4;

__device__ inline unsigned short to_bf16(float f) {
    union { float f; uint32_t u; } v; v.f = f;
    return (unsigned short)((v.u + 0x7FFFu + ((v.u >> 16) & 1u)) >> 16);
}

// ---- Kernel 1: fp32 -> bf16 convert of x (8 elems / thread) ----
__global__ __launch_bounds__(256) void convert_x_kernel(const float* __restrict__ x,
                                                        unsigned short* __restrict__ xb) {
    int idx = blockIdx.x * 256 + threadIdx.x;
    const f32x4* xv = reinterpret_cast<const f32x4*>(x);
    f32x4 v0 = xv[2 * idx];
    f32x4 v1 = xv[2 * idx + 1];
    union { bf16x8 v; unsigned short s[8]; } o;
    o.s[0] = to_bf16(v0.x); o.s[1] = to_bf16(v0.y);
    o.s[2] = to_bf16(v0.z); o.s[3] = to_bf16(v0.w);
    o.s[4] = to_bf16(v1.x); o.s[5] = to_bf16(v1.y);
    o.s[6] = to_bf16(v1.z); o.s[7] = to_bf16(v1.w);
    reinterpret_cast<bf16x8*>(xb)[idx] = o.v;
}

// ---- Kernel 2: W[o][i] = sum_b a[b][o/512][i/512] * s[b][o%512][i%512], bf16 out ----
__global__ __launch_bounds__(256) void gen_w_kernel(const float* __restrict__ a,
                                                    const float* __restrict__ s,
                                                    unsigned short* __restrict__ w) {
    int idx = blockIdx.x * 256 + threadIdx.x;   // 4096 * 512 threads
    int o  = idx >> 9;
    int i8 = idx & 511;
    int i0 = i8 * 8;
    int obig = o >> 9, orow = o & 511;
    int ibig = i0 >> 9, icol = i0 & 511;

    float acc[8];
#pragma unroll
    for (int j = 0; j < 8; ++j) acc[j] = 0.f;

#pragma unroll
    for (int b = 0; b < 8; ++b) {
        float av = a[b * 64 + obig * 8 + ibig];
        const f32x4* sv = reinterpret_cast<const f32x4*>(s + b * 512 * 512 + orow * 512 + icol);
        f32x4 s0 = sv[0], s1 = sv[1];
        acc[0] += av * s0.x; acc[1] += av * s0.y; acc[2] += av * s0.z; acc[3] += av * s0.w;
        acc[4] += av * s1.x; acc[5] += av * s1.y; acc[6] += av * s1.z; acc[7] += av * s1.w;
    }
    union { bf16x8 v; unsigned short q[8]; } ov;
#pragma unroll
    for (int j = 0; j < 8; ++j) ov.q[j] = to_bf16(acc[j]);
    reinterpret_cast<bf16x8*>(w)[idx] = ov.v;
}

// ---- Kernel 3: C[m,n] = sum_k A[m,k] * B[n,k] ----
// r7 skeleton (256x256, BK=32, 4-deep LDS ring, 8 waves 2Mx4N, XOR swizzle,
// reg fragment double-buffer, ONE {vmcnt(4); barrier} per tile) +
// WAVE-PARITY ANTI-PHASING: odd waves run [MFMA-lo, reads, MFMA-hi], even
// waves [reads, MFMA-lo, reads, MFMA-hi] -> SIMD-mates offset by one MFMA
// cluster so one wave's LDS burst executes under the other's matrix burst.
__global__ __launch_bounds__(512, 2)
void gemm_bt_kernel(const unsigned short* __restrict__ A,
                    const unsigned short* __restrict__ B,
                    float* __restrict__ C) {
    __shared__ __align__(16) unsigned short As[4][BM][BK];
    __shared__ __align__(16) unsigned short Bs[4][BN][BK];

    // XCD-aware bijective swizzle: 512 blocks, 8 XCDs, 64 blocks/XCD
    int bid = blockIdx.x;
    int swz = (bid & 7) * 64 + (bid >> 3);
    int bm = swz >> 4;                 // 16 bn-tiles per bm-row
    int bn = swz & 15;

    int tid  = threadIdx.x;
    int wid  = tid >> 6;               // 0..7
    int lane = tid & 63;
    int wm = wid >> 2, wn = wid & 3;   // wave owns 128x64 of C
    const bool odd = (wid & 1);

    // staging geometry (pre-swizzled global source, linear LDS dest)
    int srow  = lane >> 2;                              // 0..15
    int sslot = (lane & 3) ^ ((srow >> 1) & 3);
    const unsigned short* ag0 = A + (size_t)(bm * BM + wid * 16 + srow) * KTOT + sslot * 8;
    const unsigned short* ag1 = ag0 + (size_t)128 * KTOT;
    const unsigned short* bg0 = B + (size_t)(bn * BN + wid * 16 + srow) * KTOT + sslot * 8;
    const unsigned short* bg1 = bg0 + (size_t)128 * KTOT;

    // fragment-read geometry (same XOR on read side); rslot lane-constant
    int rl    = lane & 15;
    int rslot = (lane >> 4) ^ ((rl >> 1) & 3);

    f32x4 acc[8][4];
#pragma unroll
    for (int m = 0; m < 8; ++m)
#pragma unroll
        for (int n = 0; n < 4; ++n) acc[m][n] = (f32x4)0.f;

    auto STAGE_A = [&](int s, int k0) {
        __builtin_amdgcn_global_load_lds(
            (const __attribute__((address_space(1))) void*)(ag0 + k0),
            (__attribute__((address_space(3))) void*)&As[s][wid * 16][0], 16, 0, 0);
        __builtin_amdgcn_global_load_lds(
            (const __attribute__((address_space(1))) void*)(ag1 + k0),
            (__attribute__((address_space(3))) void*)&As[s][128 + wid * 16][0], 16, 0, 0);
    };
    auto STAGE_B = [&](int s, int k0) {
        __builtin_amdgcn_global_load_lds(
            (const __attribute__((address_space(1))) void*)(bg0 + k0),
            (__attribute__((address_space(3))) void*)&Bs[s][wid * 16][0], 16, 0, 0);
        __builtin_amdgcn_global_load_lds(
            (const __attribute__((address_space(1))) void*)(bg1 + k0),
            (__attribute__((address_space(3))) void*)&Bs[s][128 + wid * 16][0], 16, 0, 0);
    };

    auto LDA = [&](int s, int mi) -> bf16x8 {
        return *reinterpret_cast<const bf16x8*>(&As[s][wm * 128 + mi * 16 + rl][rslot * 8]);
    };
    auto LDB = [&](int s, int ni) -> bf16x8 {
        return *reinterpret_cast<const bf16x8*>(&Bs[s][wn * 64 + ni * 16 + rl][rslot * 8]);
    };

    // frag regs: fa/fb = current tile m0-3 + B (preloaded), ga = m4-7,
    // pa/pb = next tile's m0-3 + B
    bf16x8 fa[4], fb[4], ga[4], pa[4], pb[4];

    // ---- prologue: stage tiles 0,1,2; slots 0,1 forced resident ----
    STAGE_A(0, 0);          STAGE_B(0, 0);
    STAGE_A(1, BK);         STAGE_B(1, BK);
    STAGE_A(2, 2 * BK);     STAGE_B(2, 2 * BK);
    asm volatile("s_waitcnt vmcnt(4)" ::: "memory");
    __builtin_amdgcn_s_barrier();
#pragma unroll
    for (int m = 0; m < 4; ++m) fa[m] = LDA(0, m);
#pragma unroll
    for (int n = 0; n < 4; ++n) fb[n] = LDB(0, n);

    // ---- main loop: all 128 tiles; slots compile-time via x4 unroll ----
    for (int tb = 0; tb < NT; tb += 4) {
#pragma unroll
        for (int u = 0; u < 4; ++u) {
            const int t  = tb + u;
            const int s  = u;
            const int nx = (u + 1) & 3;
            const int ss = (u + 3) & 3;
            const bool st = (t + 3) < NT;
            const int k0 = (t + 3) * BK;

            if (!odd) {
                // EVEN: [R4(ga); stageA; lgkm4; M16lo; R8(pa,pb); stageB; lgkm8; M16hi]
#pragma unroll
                for (int m = 0; m < 4; ++m) ga[m] = LDA(s, m + 4);
                if (st) STAGE_A(ss, k0);
                asm volatile("s_waitcnt lgkmcnt(4)" ::: "memory");   // fa,fb ready
                __builtin_amdgcn_sched_barrier(0);
                __builtin_amdgcn_s_setprio(1);
#pragma unroll
                for (int m = 0; m < 4; ++m)
#pragma unroll
                    for (int n = 0; n < 4; ++n)
                        acc[m][n] = __builtin_amdgcn_mfma_f32_16x16x32_bf16(fa[m], fb[n], acc[m][n], 0, 0, 0);
                __builtin_amdgcn_s_setprio(0);
#pragma unroll
                for (int m = 0; m < 4; ++m) pa[m] = LDA(nx, m);
#pragma unroll
                for (int n = 0; n < 4; ++n) pb[n] = LDB(nx, n);
                if (st) STAGE_B(ss, k0);
                asm volatile("s_waitcnt lgkmcnt(8)" ::: "memory");   // ga ready
                __builtin_amdgcn_sched_barrier(0);
                __builtin_amdgcn_s_setprio(1);
#pragma unroll
                for (int m = 0; m < 4; ++m)
#pragma unroll
                    for (int n = 0; n < 4; ++n)
                        acc[m + 4][n] = __builtin_amdgcn_mfma_f32_16x16x32_bf16(ga[m], fb[n], acc[m + 4][n], 0, 0, 0);
                __builtin_amdgcn_s_setprio(0);
            } else {
                // ODD: [lgkm0; M16lo; R4(ga); R8(pa,pb); stageA+B; lgkm8; M16hi]
                asm volatile("s_waitcnt lgkmcnt(0)" ::: "memory");   // fa,fb ready
                __builtin_amdgcn_sched_barrier(0);
                __builtin_amdgcn_s_setprio(1);
#pragma unroll
                for (int m = 0; m < 4; ++m)
#pragma unroll
                    for (int n = 0; n < 4; ++n)
                        acc[m][n] = __builtin_amdgcn_mfma_f32_16x16x32_bf16(fa[m], fb[n], acc[m][n], 0, 0, 0);
                __builtin_amdgcn_s_setprio(0);
#pragma unroll
                for (int m = 0; m < 4; ++m) ga[m] = LDA(s, m + 4);
                if (st) STAGE_A(ss, k0);
#pragma unroll
                for (int m = 0; m < 4; ++m) pa[m] = LDA(nx, m);
#pragma unroll
                for (int n = 0; n < 4; ++n) pb[n] = LDB(nx, n);
                if (st) STAGE_B(ss, k0);
                asm volatile("s_waitcnt lgkmcnt(8)" ::: "memory");   // ga ready
                __builtin_amdgcn_sched_barrier(0);
                __builtin_amdgcn_s_setprio(1);
#pragma unroll
                for (int m = 0; m < 4; ++m)
#pragma unroll
                    for (int n = 0; n < 4; ++n)
                        acc[m + 4][n] = __builtin_amdgcn_mfma_f32_16x16x32_bf16(ga[m], fb[n], acc[m + 4][n], 0, 0, 0);
                __builtin_amdgcn_s_setprio(0);
            }

            // ---- tile end: single sync. Forces slot (t+2)&3 resident for
            // next tile's prefetches; orders slot-s reads before restage. ----
            asm volatile("s_waitcnt vmcnt(4)" ::: "memory");
            __builtin_amdgcn_s_barrier();

            // rotate frag buffers (compiler renames; no movs after unroll)
#pragma unroll
            for (int m = 0; m < 4; ++m) fa[m] = pa[m];
#pragma unroll
            for (int n = 0; n < 4; ++n) fb[n] = pb[n];
        }
    }

    // ---- C write: per 16x16 frag, col = lane&15, row = (lane>>4)*4 + j ----
    int crow0 = bm * BM + wm * 128 + (lane >> 4) * 4;
    int ccol0 = bn * BN + wn * 64 + (lane & 15);
#pragma unroll
    for (int m = 0; m < 8; ++m)
#pragma unroll
        for (int n = 0; n < 4; ++n)
#pragma unroll
            for (int j = 0; j < 4; ++j) {
                size_t r = (size_t)(crow0 + m * 16 + j);
                size_t c = (size_t)(ccol0 + n * 16);
                C[r * NTOT + c] = acc[m][n][j];
            }
}

} // anonymous namespace

extern "C" void kernel_launch(void* const* d_in, const int* in_sizes, int n_in,
                              void* d_out, int out_size, void* d_ws, size_t ws_size,
                              hipStream_t stream) {
    const float* x = (const float*)d_in[0];   // (4,2048,4096) f32
    const float* a = (const float*)d_in[1];   // (8,8,8) f32
    const float* s = (const float*)d_in[2];   // (8,512,512) f32
    float* out = (float*)d_out;               // (4,2048,4096) f32

    unsigned short* xb = (unsigned short*)d_ws;                    // 64 MiB bf16 x
    unsigned short* wb = xb + (size_t)MTOT * KTOT;                 // 32 MiB bf16 W

    convert_x_kernel<<<(MTOT * KTOT / 8) / 256, 256, 0, stream>>>(x, xb);
    gen_w_kernel<<<(NTOT * KTOT / 8) / 256, 256, 0, stream>>>(a, s, wb);
    gemm_bt_kernel<<<(MTOT / 256) * (NTOT / 256), 512, 0, stream>>>(xb, wb, out);
}

// Round 12
// 333.560 us; speedup vs baseline: 6.4646x; 6.4646x over previous
//
#include <hip/hip_runtime.h>
#include <hip/hip_bf16.h>
#include <stdint.h>

namespace {

constexpr int MTOT = 8192;   // 4 * 2048 rows of x
constexpr int NTOT = 4096;   // OUT_DIM
constexpr int KTOT = 4096;   // IN_DIM

constexpr int BM = 256, BN = 256, BK = 32;
constexpr int NT = KTOT / BK;     // 128 K-tiles

typedef __attribute__((ext_vector_type(8))) short bf16x8;
typedef __attribute__((ext_vector_type(4))) float f32x4;

__device__ inline unsigned short to_bf16(float f) {
    union { float f; uint32_t u; } v; v.f = f;
    return (unsigned short)((v.u + 0x7FFFu + ((v.u >> 16) & 1u)) >> 16);
}

// ---- Kernel 1: fp32 -> bf16 convert of x (8 elems / thread) ----
__global__ __launch_bounds__(256) void convert_x_kernel(const float* __restrict__ x,
                                                        unsigned short* __restrict__ xb) {
    int idx = blockIdx.x * 256 + threadIdx.x;
    const f32x4* xv = reinterpret_cast<const f32x4*>(x);
    f32x4 v0 = xv[2 * idx];
    f32x4 v1 = xv[2 * idx + 1];
    union { bf16x8 v; unsigned short s[8]; } o;
    o.s[0] = to_bf16(v0.x); o.s[1] = to_bf16(v0.y);
    o.s[2] = to_bf16(v0.z); o.s[3] = to_bf16(v0.w);
    o.s[4] = to_bf16(v1.x); o.s[5] = to_bf16(v1.y);
    o.s[6] = to_bf16(v1.z); o.s[7] = to_bf16(v1.w);
    reinterpret_cast<bf16x8*>(xb)[idx] = o.v;
}

// ---- Kernel 2: W[o][i] = sum_b a[b][o/512][i/512] * s[b][o%512][i%512], bf16 out ----
__global__ __launch_bounds__(256) void gen_w_kernel(const float* __restrict__ a,
                                                    const float* __restrict__ s,
                                                    unsigned short* __restrict__ w) {
    int idx = blockIdx.x * 256 + threadIdx.x;   // 4096 * 512 threads
    int o  = idx >> 9;
    int i8 = idx & 511;
    int i0 = i8 * 8;
    int obig = o >> 9, orow = o & 511;
    int ibig = i0 >> 9, icol = i0 & 511;

    float acc[8];
#pragma unroll
    for (int j = 0; j < 8; ++j) acc[j] = 0.f;

#pragma unroll
    for (int b = 0; b < 8; ++b) {
        float av = a[b * 64 + obig * 8 + ibig];
        const f32x4* sv = reinterpret_cast<const f32x4*>(s + b * 512 * 512 + orow * 512 + icol);
        f32x4 s0 = sv[0], s1 = sv[1];
        acc[0] += av * s0.x; acc[1] += av * s0.y; acc[2] += av * s0.z; acc[3] += av * s0.w;
        acc[4] += av * s1.x; acc[5] += av * s1.y; acc[6] += av * s1.z; acc[7] += av * s1.w;
    }
    union { bf16x8 v; unsigned short q[8]; } ov;
#pragma unroll
    for (int j = 0; j < 8; ++j) ov.q[j] = to_bf16(acc[j]);
    reinterpret_cast<bf16x8*>(w)[idx] = ov.v;
}

// ---- Kernel 3: C[m,n] = sum_k A[m,k] * B[n,k] ----
// r7 skeleton + SIMD-mate anti-phasing. Waves 0-3 ("even", SIMDs 0-3) run
// [reads; MFMA-lo; reads; MFMA-hi]; waves 4-7 ("odd", same SIMDs) run
// [MFMA-lo; reads; MFMA-hi] on prefetched frags. Each SIMD hosts one of
// each -> its mate MFMAs while this wave's LDS burst is serviced.
// Spill-safe: TWO complete loop copies (no in-loop branch join).
__global__ __launch_bounds__(512, 2)
void gemm_bt_kernel(const unsigned short* __restrict__ A,
                    const unsigned short* __restrict__ B,
                    float* __restrict__ C) {
    __shared__ __align__(16) unsigned short As[4][BM][BK];
    __shared__ __align__(16) unsigned short Bs[4][BN][BK];

    // XCD-aware bijective swizzle: 512 blocks, 8 XCDs, 64 blocks/XCD
    int bid = blockIdx.x;
    int swz = (bid & 7) * 64 + (bid >> 3);
    int bm = swz >> 4;                 // 16 bn-tiles per bm-row
    int bn = swz & 15;

    int tid  = threadIdx.x;
    int wid  = tid >> 6;               // 0..7
    int lane = tid & 63;
    int wm = wid >> 2, wn = wid & 3;   // wave owns 128x64 of C

    // staging geometry (pre-swizzled global source, linear LDS dest)
    int srow  = lane >> 2;                              // 0..15
    int sslot = (lane & 3) ^ ((srow >> 1) & 3);
    const unsigned short* ag0 = A + (size_t)(bm * BM + wid * 16 + srow) * KTOT + sslot * 8;
    const unsigned short* ag1 = ag0 + (size_t)128 * KTOT;
    const unsigned short* bg0 = B + (size_t)(bn * BN + wid * 16 + srow) * KTOT + sslot * 8;
    const unsigned short* bg1 = bg0 + (size_t)128 * KTOT;

    // fragment-read geometry (same XOR on read side); rslot lane-constant
    int rl    = lane & 15;
    int rslot = (lane >> 4) ^ ((rl >> 1) & 3);

    f32x4 acc[8][4];
#pragma unroll
    for (int m = 0; m < 8; ++m)
#pragma unroll
        for (int n = 0; n < 4; ++n) acc[m][n] = (f32x4)0.f;

    auto STAGE_A = [&](int s, int k0) {
        __builtin_amdgcn_global_load_lds(
            (const __attribute__((address_space(1))) void*)(ag0 + k0),
            (__attribute__((address_space(3))) void*)&As[s][wid * 16][0], 16, 0, 0);
        __builtin_amdgcn_global_load_lds(
            (const __attribute__((address_space(1))) void*)(ag1 + k0),
            (__attribute__((address_space(3))) void*)&As[s][128 + wid * 16][0], 16, 0, 0);
    };
    auto STAGE_B = [&](int s, int k0) {
        __builtin_amdgcn_global_load_lds(
            (const __attribute__((address_space(1))) void*)(bg0 + k0),
            (__attribute__((address_space(3))) void*)&Bs[s][wid * 16][0], 16, 0, 0);
        __builtin_amdgcn_global_load_lds(
            (const __attribute__((address_space(1))) void*)(bg1 + k0),
            (__attribute__((address_space(3))) void*)&Bs[s][128 + wid * 16][0], 16, 0, 0);
    };

    auto LDA = [&](int s, int mi) -> bf16x8 {
        return *reinterpret_cast<const bf16x8*>(&As[s][wm * 128 + mi * 16 + rl][rslot * 8]);
    };
    auto LDB = [&](int s, int ni) -> bf16x8 {
        return *reinterpret_cast<const bf16x8*>(&Bs[s][wn * 64 + ni * 16 + rl][rslot * 8]);
    };

    bf16x8 fa[4], fb[4], ga[4], pa[4], pb[4];

    // ---- prologue: stage tiles 0,1,2; slots 0,1 forced resident ----
    STAGE_A(0, 0);          STAGE_B(0, 0);
    STAGE_A(1, BK);         STAGE_B(1, BK);
    STAGE_A(2, 2 * BK);     STAGE_B(2, 2 * BK);
    asm volatile("s_waitcnt vmcnt(4)" ::: "memory");
    __builtin_amdgcn_s_barrier();
#pragma unroll
    for (int m = 0; m < 4; ++m) fa[m] = LDA(0, m);
#pragma unroll
    for (int n = 0; n < 4; ++n) fb[n] = LDB(0, n);

    if (wid < 4) {
        // ================= EVEN waves (one per SIMD): r7 schedule =================
        for (int tb = 0; tb < NT; tb += 4) {
#pragma unroll
            for (int u = 0; u < 4; ++u) {
                const int t  = tb + u;
                const int s  = u;
                const int nx = (u + 1) & 3;
                const int ss = (u + 3) & 3;
                const bool st = (t + 3) < NT;
                const int k0 = (t + 3) * BK;

#pragma unroll
                for (int m = 0; m < 4; ++m) ga[m] = LDA(s, m + 4);
                if (st) STAGE_A(ss, k0);
                asm volatile("s_waitcnt lgkmcnt(4)" ::: "memory");   // fa,fb ready
                __builtin_amdgcn_sched_barrier(0);
                __builtin_amdgcn_s_setprio(1);
#pragma unroll
                for (int m = 0; m < 4; ++m)
#pragma unroll
                    for (int n = 0; n < 4; ++n)
                        acc[m][n] = __builtin_amdgcn_mfma_f32_16x16x32_bf16(fa[m], fb[n], acc[m][n], 0, 0, 0);
                __builtin_amdgcn_s_setprio(0);

#pragma unroll
                for (int m = 0; m < 4; ++m) pa[m] = LDA(nx, m);
#pragma unroll
                for (int n = 0; n < 4; ++n) pb[n] = LDB(nx, n);
                if (st) STAGE_B(ss, k0);
                asm volatile("s_waitcnt lgkmcnt(8)" ::: "memory");   // ga ready
                __builtin_amdgcn_sched_barrier(0);
                __builtin_amdgcn_s_setprio(1);
#pragma unroll
                for (int m = 0; m < 4; ++m)
#pragma unroll
                    for (int n = 0; n < 4; ++n)
                        acc[m + 4][n] = __builtin_amdgcn_mfma_f32_16x16x32_bf16(ga[m], fb[n], acc[m + 4][n], 0, 0, 0);
                __builtin_amdgcn_s_setprio(0);

                asm volatile("s_waitcnt vmcnt(4)" ::: "memory");
                __builtin_amdgcn_s_barrier();
#pragma unroll
                for (int m = 0; m < 4; ++m) fa[m] = pa[m];
#pragma unroll
                for (int n = 0; n < 4; ++n) fb[n] = pb[n];
            }
        }
    } else {
        // ================= ODD waves (one per SIMD): MFMA-first =================
        for (int tb = 0; tb < NT; tb += 4) {
#pragma unroll
            for (int u = 0; u < 4; ++u) {
                const int t  = tb + u;
                const int s  = u;
                const int nx = (u + 1) & 3;
                const int ss = (u + 3) & 3;
                const bool st = (t + 3) < NT;
                const int k0 = (t + 3) * BK;

                // MFMA-lo first, on frags prefetched last tile (drain all reads)
                asm volatile("s_waitcnt lgkmcnt(0)" ::: "memory");
                __builtin_amdgcn_sched_barrier(0);
                __builtin_amdgcn_s_setprio(1);
#pragma unroll
                for (int m = 0; m < 4; ++m)
#pragma unroll
                    for (int n = 0; n < 4; ++n)
                        acc[m][n] = __builtin_amdgcn_mfma_f32_16x16x32_bf16(fa[m], fb[n], acc[m][n], 0, 0, 0);
                __builtin_amdgcn_s_setprio(0);

                // all 12 reads + both stages in one burst
#pragma unroll
                for (int m = 0; m < 4; ++m) ga[m] = LDA(s, m + 4);
#pragma unroll
                for (int m = 0; m < 4; ++m) pa[m] = LDA(nx, m);
#pragma unroll
                for (int n = 0; n < 4; ++n) pb[n] = LDB(nx, n);
                if (st) { STAGE_A(ss, k0); STAGE_B(ss, k0); }
                asm volatile("s_waitcnt lgkmcnt(8)" ::: "memory");   // ga ready
                __builtin_amdgcn_sched_barrier(0);
                __builtin_amdgcn_s_setprio(1);
#pragma unroll
                for (int m = 0; m < 4; ++m)
#pragma unroll
                    for (int n = 0; n < 4; ++n)
                        acc[m + 4][n] = __builtin_amdgcn_mfma_f32_16x16x32_bf16(ga[m], fb[n], acc[m + 4][n], 0, 0, 0);
                __builtin_amdgcn_s_setprio(0);

                asm volatile("s_waitcnt vmcnt(4)" ::: "memory");
                __builtin_amdgcn_s_barrier();
#pragma unroll
                for (int m = 0; m < 4; ++m) fa[m] = pa[m];
#pragma unroll
                for (int n = 0; n < 4; ++n) fb[n] = pb[n];
            }
        }
    }

    // ---- C write: per 16x16 frag, col = lane&15, row = (lane>>4)*4 + j ----
    int crow0 = bm * BM + wm * 128 + (lane >> 4) * 4;
    int ccol0 = bn * BN + wn * 64 + (lane & 15);
#pragma unroll
    for (int m = 0; m < 8; ++m)
#pragma unroll
        for (int n = 0; n < 4; ++n)
#pragma unroll
            for (int j = 0; j < 4; ++j) {
                size_t r = (size_t)(crow0 + m * 16 + j);
                size_t c = (size_t)(ccol0 + n * 16);
                C[r * NTOT + c] = acc[m][n][j];
            }
}

} // anonymous namespace

extern "C" void kernel_launch(void* const* d_in, const int* in_sizes, int n_in,
                              void* d_out, int out_size, void* d_ws, size_t ws_size,
                              hipStream_t stream) {
    const float* x = (const float*)d_in[0];   // (4,2048,4096) f32
    const float* a = (const float*)d_in[1];   // (8,8,8) f32
    const float* s = (const float*)d_in[2];   // (8,512,512) f32
    float* out = (float*)d_out;               // (4,2048,4096) f32

    unsigned short* xb = (unsigned short*)d_ws;                    // 64 MiB bf16 x
    unsigned short* wb = xb + (size_t)MTOT * KTOT;                 // 32 MiB bf16 W

    convert_x_kernel<<<(MTOT * KTOT / 8) / 256, 256, 0, stream>>>(x, xb);
    gen_w_kernel<<<(NTOT * KTOT / 8) / 256, 256, 0, stream>>>(a, s, wb);
    gemm_bt_kernel<<<(MTOT / 256) * (NTOT / 256), 512, 0, stream>>>(xb, wb, out);
}

// Round 13
// 289.776 us; speedup vs baseline: 7.4414x; 1.1511x over previous
//
#include <hip/hip_runtime.h>
#include <hip/hip_bf16.h>
#include <stdint.h>

namespace {

constexpr int MTOT = 8192;   // 4 * 2048 rows of x
constexpr int NTOT = 4096;   // OUT_DIM
constexpr int KTOT = 4096;   // IN_DIM

constexpr int BM = 256, BN = 256, BK = 32;
constexpr int NT = KTOT / BK;     // 128 K-tiles

constexpr int CONV_BLOCKS = (MTOT * KTOT / 8) / 256;   // 16384
constexpr int GENW_BLOCKS = (NTOT * KTOT / 8) / 256;   // 8192

typedef __attribute__((ext_vector_type(8))) short bf16x8;
typedef __attribute__((ext_vector_type(4))) float f32x4;

__device__ inline unsigned short to_bf16(float f) {
    union { float f; uint32_t u; } v; v.f = f;
    return (unsigned short)((v.u + 0x7FFFu + ((v.u >> 16) & 1u)) >> 16);
}

// ---- Kernel 1: merged prep. Blocks [0,16384): x fp32->bf16. Blocks
// [16384, 24576): W[o][i] = sum_b a[b][o/512][i/512]*s[b][o%512][i%512].
// Block-uniform branch; both paths memory-bound and fully vectorized.
__global__ __launch_bounds__(256) void prep_kernel(const float* __restrict__ x,
                                                   const float* __restrict__ a,
                                                   const float* __restrict__ s,
                                                   unsigned short* __restrict__ xb,
                                                   unsigned short* __restrict__ wb) {
    if (blockIdx.x < CONV_BLOCKS) {
        int idx = blockIdx.x * 256 + threadIdx.x;
        const f32x4* xv = reinterpret_cast<const f32x4*>(x);
        f32x4 v0 = xv[2 * idx];
        f32x4 v1 = xv[2 * idx + 1];
        union { bf16x8 v; unsigned short q[8]; } o;
        o.q[0] = to_bf16(v0.x); o.q[1] = to_bf16(v0.y);
        o.q[2] = to_bf16(v0.z); o.q[3] = to_bf16(v0.w);
        o.q[4] = to_bf16(v1.x); o.q[5] = to_bf16(v1.y);
        o.q[6] = to_bf16(v1.z); o.q[7] = to_bf16(v1.w);
        reinterpret_cast<bf16x8*>(xb)[idx] = o.v;
    } else {
        int idx = (blockIdx.x - CONV_BLOCKS) * 256 + threadIdx.x;
        int o  = idx >> 9;
        int i8 = idx & 511;
        int i0 = i8 * 8;
        int obig = o >> 9, orow = o & 511;
        int ibig = i0 >> 9, icol = i0 & 511;

        float acc[8];
#pragma unroll
        for (int j = 0; j < 8; ++j) acc[j] = 0.f;
#pragma unroll
        for (int b = 0; b < 8; ++b) {
            float av = a[b * 64 + obig * 8 + ibig];
            const f32x4* sv = reinterpret_cast<const f32x4*>(s + b * 512 * 512 + orow * 512 + icol);
            f32x4 s0 = sv[0], s1 = sv[1];
            acc[0] += av * s0.x; acc[1] += av * s0.y; acc[2] += av * s0.z; acc[3] += av * s0.w;
            acc[4] += av * s1.x; acc[5] += av * s1.y; acc[6] += av * s1.z; acc[7] += av * s1.w;
        }
        union { bf16x8 v; unsigned short q[8]; } ov;
#pragma unroll
        for (int j = 0; j < 8; ++j) ov.q[j] = to_bf16(acc[j]);
        reinterpret_cast<bf16x8*>(wb)[idx] = ov.v;
    }
}

// ---- Kernel 2: C[m,n] = sum_k A[m,k] * B[n,k]  (exact r7 structure) ----
// 256x256 tile, BK=32, 4-deep LDS ring, 8 waves 2Mx4N, XOR swizzle,
// register fragment double-buffer, ONE {vmcnt(4); s_barrier} per K-tile.
// Ten schedule variants bracket 42-49% MfmaUtil; this is the robust best.
__global__ __launch_bounds__(512, 2)
void gemm_bt_kernel(const unsigned short* __restrict__ A,
                    const unsigned short* __restrict__ B,
                    float* __restrict__ C) {
    __shared__ __align__(16) unsigned short As[4][BM][BK];
    __shared__ __align__(16) unsigned short Bs[4][BN][BK];

    // XCD-aware bijective swizzle: 512 blocks, 8 XCDs, 64 blocks/XCD
    int bid = blockIdx.x;
    int swz = (bid & 7) * 64 + (bid >> 3);
    int bm = swz >> 4;                 // 16 bn-tiles per bm-row
    int bn = swz & 15;

    int tid  = threadIdx.x;
    int wid  = tid >> 6;               // 0..7
    int lane = tid & 63;
    int wm = wid >> 2, wn = wid & 3;   // wave owns 128x64 of C

    // staging geometry (pre-swizzled global source, linear LDS dest)
    int srow  = lane >> 2;                              // 0..15
    int sslot = (lane & 3) ^ ((srow >> 1) & 3);
    const unsigned short* ag0 = A + (size_t)(bm * BM + wid * 16 + srow) * KTOT + sslot * 8;
    const unsigned short* ag1 = ag0 + (size_t)128 * KTOT;
    const unsigned short* bg0 = B + (size_t)(bn * BN + wid * 16 + srow) * KTOT + sslot * 8;
    const unsigned short* bg1 = bg0 + (size_t)128 * KTOT;

    // fragment-read geometry (same XOR on read side); rslot lane-constant
    int rl    = lane & 15;
    int rslot = (lane >> 4) ^ ((rl >> 1) & 3);

    f32x4 acc[8][4];
#pragma unroll
    for (int m = 0; m < 8; ++m)
#pragma unroll
        for (int n = 0; n < 4; ++n) acc[m][n] = (f32x4)0.f;

    auto STAGE_A = [&](int s, int k0) {
        __builtin_amdgcn_global_load_lds(
            (const __attribute__((address_space(1))) void*)(ag0 + k0),
            (__attribute__((address_space(3))) void*)&As[s][wid * 16][0], 16, 0, 0);
        __builtin_amdgcn_global_load_lds(
            (const __attribute__((address_space(1))) void*)(ag1 + k0),
            (__attribute__((address_space(3))) void*)&As[s][128 + wid * 16][0], 16, 0, 0);
    };
    auto STAGE_B = [&](int s, int k0) {
        __builtin_amdgcn_global_load_lds(
            (const __attribute__((address_space(1))) void*)(bg0 + k0),
            (__attribute__((address_space(3))) void*)&Bs[s][wid * 16][0], 16, 0, 0);
        __builtin_amdgcn_global_load_lds(
            (const __attribute__((address_space(1))) void*)(bg1 + k0),
            (__attribute__((address_space(3))) void*)&Bs[s][128 + wid * 16][0], 16, 0, 0);
    };

    auto LDA = [&](int s, int mi) -> bf16x8 {
        return *reinterpret_cast<const bf16x8*>(&As[s][wm * 128 + mi * 16 + rl][rslot * 8]);
    };
    auto LDB = [&](int s, int ni) -> bf16x8 {
        return *reinterpret_cast<const bf16x8*>(&Bs[s][wn * 64 + ni * 16 + rl][rslot * 8]);
    };

    // fragment registers: fa/fb consumed in PH0, ga consumed in PH1,
    // pa/pb = next tile's PH0 frags (prefetched in PH1)
    bf16x8 fa[4], fb[4], ga[4], pa[4], pb[4];

    // ---- prologue: stage tiles 0,1,2 (12 loads); slots 0,1 forced resident ----
    STAGE_A(0, 0);          STAGE_B(0, 0);
    STAGE_A(1, BK);         STAGE_B(1, BK);
    STAGE_A(2, 2 * BK);     STAGE_B(2, 2 * BK);
    asm volatile("s_waitcnt vmcnt(4)" ::: "memory");
    __builtin_amdgcn_s_barrier();
    // prime current frags for tile 0 PH0 (completion forced by first lgkmcnt(4))
#pragma unroll
    for (int m = 0; m < 4; ++m) fa[m] = LDA(0, m);
#pragma unroll
    for (int n = 0; n < 4; ++n) fb[n] = LDB(0, n);

    // ---- main loop: all 128 tiles; slots compile-time via x4 unroll ----
    for (int tb = 0; tb < NT; tb += 4) {
#pragma unroll
        for (int u = 0; u < 4; ++u) {
            const int t  = tb + u;
            const int s  = u;
            const int nx = (u + 1) & 3;
            const int ss = (u + 3) & 3;
            const bool st = (t + 3) < NT;
            const int k0 = (t + 3) * BK;

            // ---- PH0: prefetch ga = A(s, m4-7); stage A(t+3); MFMA m0-3 on fa,fb ----
#pragma unroll
            for (int m = 0; m < 4; ++m) ga[m] = LDA(s, m + 4);
            if (st) STAGE_A(ss, k0);
            asm volatile("s_waitcnt lgkmcnt(4)" ::: "memory");   // forces fa,fb complete
            __builtin_amdgcn_sched_barrier(0);
            __builtin_amdgcn_s_setprio(1);
#pragma unroll
            for (int m = 0; m < 4; ++m)
#pragma unroll
                for (int n = 0; n < 4; ++n)
                    acc[m][n] = __builtin_amdgcn_mfma_f32_16x16x32_bf16(fa[m], fb[n], acc[m][n], 0, 0, 0);
            __builtin_amdgcn_s_setprio(0);

            // ---- PH1: prefetch pa,pb = tile t+1 PH0 frags; stage B(t+3); MFMA m4-7 ----
#pragma unroll
            for (int m = 0; m < 4; ++m) pa[m] = LDA(nx, m);
#pragma unroll
            for (int n = 0; n < 4; ++n) pb[n] = LDB(nx, n);
            if (st) STAGE_B(ss, k0);
            asm volatile("s_waitcnt lgkmcnt(8)" ::: "memory");   // forces ga complete
            __builtin_amdgcn_sched_barrier(0);
            __builtin_amdgcn_s_setprio(1);
#pragma unroll
            for (int m = 0; m < 4; ++m)
#pragma unroll
                for (int n = 0; n < 4; ++n)
                    acc[m + 4][n] = __builtin_amdgcn_mfma_f32_16x16x32_bf16(ga[m], fb[n], acc[m + 4][n], 0, 0, 0);
            __builtin_amdgcn_s_setprio(0);

            // ---- tile end: the ONLY barrier. Forces slot (t+2)&3 resident for
            // next tile's prefetches; orders slot-s reads before restage. ----
            asm volatile("s_waitcnt vmcnt(4)" ::: "memory");
            __builtin_amdgcn_s_barrier();

            // rotate frag buffers (compiler renames; no movs after unroll)
#pragma unroll
            for (int m = 0; m < 4; ++m) fa[m] = pa[m];
#pragma unroll
            for (int n = 0; n < 4; ++n) fb[n] = pb[n];
        }
    }

    // ---- C write: per 16x16 frag, col = lane&15, row = (lane>>4)*4 + j ----
    int crow0 = bm * BM + wm * 128 + (lane >> 4) * 4;
    int ccol0 = bn * BN + wn * 64 + (lane & 15);
#pragma unroll
    for (int m = 0; m < 8; ++m)
#pragma unroll
        for (int n = 0; n < 4; ++n)
#pragma unroll
            for (int j = 0; j < 4; ++j) {
                size_t r = (size_t)(crow0 + m * 16 + j);
                size_t c = (size_t)(ccol0 + n * 16);
                C[r * NTOT + c] = acc[m][n][j];
            }
}

} // anonymous namespace

extern "C" void kernel_launch(void* const* d_in, const int* in_sizes, int n_in,
                              void* d_out, int out_size, void* d_ws, size_t ws_size,
                              hipStream_t stream) {
    const float* x = (const float*)d_in[0];   // (4,2048,4096) f32
    const float* a = (const float*)d_in[1];   // (8,8,8) f32
    const float* s = (const float*)d_in[2];   // (8,512,512) f32
    float* out = (float*)d_out;               // (4,2048,4096) f32

    unsigned short* xb = (unsigned short*)d_ws;                    // 64 MiB bf16 x
    unsigned short* wb = xb + (size_t)MTOT * KTOT;                 // 32 MiB bf16 W

    prep_kernel<<<CONV_BLOCKS + GENW_BLOCKS, 256, 0, stream>>>(x, a, s, xb, wb);
    gemm_bt_kernel<<<(MTOT / 256) * (NTOT / 256), 512, 0, stream>>>(xb, wb, out);
}